// Round 10
// baseline (417.475 us; speedup 1.0000x reference)
//
#include <hip/hip_runtime.h>

#define GAMMA 0.1f

typedef unsigned short u16;
typedef u16 u16x8 __attribute__((ext_vector_type(8)));
typedef short s16x8 __attribute__((ext_vector_type(8)));
typedef float f32x4 __attribute__((ext_vector_type(4)));
typedef unsigned int ui32x4 __attribute__((ext_vector_type(4)));

__device__ __forceinline__ float b2f(u16 u) {
  return __uint_as_float(((unsigned)u) << 16);
}
__device__ __forceinline__ u16 f2bf(float f) {
  unsigned u = __float_as_uint(f);
  unsigned r = (u + 0x7FFFu + ((u >> 16) & 1u)) >> 16;
  return (u16)r;
}
// pack two f32 -> one u32 holding (bf16(lo) | bf16(hi)<<16)
__device__ __forceinline__ unsigned pk_bf16(float lo, float hi) {
  return (unsigned)f2bf(lo) | ((unsigned)f2bf(hi) << 16);
}

// async global->LDS, 16B per lane; lds base must be wave-uniform, HW adds lane*16
__device__ __forceinline__ void gl2lds16(const u16* g, u16* l) {
  __builtin_amdgcn_global_load_lds(
      (const __attribute__((address_space(1))) unsigned int*)g,
      (__attribute__((address_space(3))) unsigned int*)l, 16, 0, 0);
}

// XCD-aware bijective swizzle (requires nwg % 8 == 0)
__device__ __forceinline__ int xcd_swz(int phys, int nwg) {
  return (phys & 7) * (nwg >> 3) + (phys >> 3);
}

// ---------------------------------------------------------------------------
// prep_all: one launch for all preprocessing.
// ---------------------------------------------------------------------------
#define PREP_NCONV 9216
#define PREP_T0 9216
#define PREP_T1 10240
#define PREP_T2 11264
#define PREP_T3 12288
#define PREP_T4 12544
#define PREP_T5 13568
#define PREP_NB 13577

__device__ __forceinline__ void tr_block(
    const float* __restrict__ src, u16* __restrict__ dst, int N, int blk, int tid)
{
  int idx = blk * 256 + tid;
  int nn = idx >> 9, kk = idx & 511;
  dst[idx] = f2bf(src[kk * N + nn]);
}

__global__ __launch_bounds__(256) void prep_all(
    const float* __restrict__ h0, const float* __restrict__ h1,
    u16* __restrict__ d0, u16* __restrict__ d1,
    const float* __restrict__ Wq, const float* __restrict__ Wk,
    const float* __restrict__ Wv, const float* __restrict__ Wp1,
    const float* __restrict__ Wo,
    const float* __restrict__ bq, const float* __restrict__ bk,
    const float* __restrict__ bv, const float* __restrict__ bp1,
    const float* __restrict__ bo,
    u16* __restrict__ WqT, u16* __restrict__ KVPW, u16* __restrict__ WoT,
    float* __restrict__ biasQ, float* __restrict__ biasKVP,
    float* __restrict__ biasO)
{
  __shared__ __align__(16) u16 T[64 * 64];
  const int b = blockIdx.x;
  const int tid = threadIdx.x;

  if (b < PREP_NCONV) {
    const int z = b / 4608;
    const int r_ = b - z * 4608;
    const int bt = r_ / 72;
    const int xx = r_ - bt * 72;
    const int kt = xx & 7, st = xx >> 3;
    const float* src = (z ? h1 : h0) + (size_t)bt * (512 * 576);
    u16* dst = (z ? d1 : d0) + (size_t)bt * (576 * 512);

    const int s = tid & 63, kc = tid >> 6;
    const float* sp = src + (size_t)(kt * 64 + kc * 16) * 576 + st * 64 + s;
    unsigned pk[8];
#pragma unroll
    for (int i = 0; i < 8; ++i) {
      float lo = sp[(2 * i) * 576];
      float hi = sp[(2 * i + 1) * 576];
      pk[i] = pk_bf16(lo, hi);
    }
    ui32x4 v0 = {pk[0], pk[1], pk[2], pk[3]};
    ui32x4 v1 = {pk[4], pk[5], pk[6], pk[7]};
    *(ui32x4*)&T[s * 64 + (((kc * 2)     ^ (s & 7)) * 8)] = v0;
    *(ui32x4*)&T[s * 64 + (((kc * 2 + 1) ^ (s & 7)) * 8)] = v1;
    __syncthreads();
    const int r = tid >> 2, oc = (tid & 3) * 2;
    ui32x4 w0 = *(const ui32x4*)&T[r * 64 + ((oc       ^ (r & 7)) * 8)];
    ui32x4 w1 = *(const ui32x4*)&T[r * 64 + (((oc + 1) ^ (r & 7)) * 8)];
    u16* dp = dst + (size_t)(st * 64 + r) * 512 + kt * 64 + oc * 8;
    *(ui32x4*)dp = w0;
    *(ui32x4*)(dp + 8) = w1;
  } else if (b < PREP_T1) {
    tr_block(Wq, WqT, 512, b - PREP_T0, tid);
  } else if (b < PREP_T2) {
    tr_block(Wk, KVPW, 512, b - PREP_T1, tid);
  } else if (b < PREP_T3) {
    tr_block(Wv, KVPW + 512 * 512, 512, b - PREP_T2, tid);
  } else if (b < PREP_T4) {
    tr_block(Wp1, KVPW + 1024 * 512, 128, b - PREP_T3, tid);
  } else if (b < PREP_T5) {
    tr_block(Wo, WoT, 512, b - PREP_T4, tid);
  } else {
    int i = (b - PREP_T5) * 256 + tid;
    if (i < 512) {
      biasQ[i] = bq[i];
    } else if (i < 1664) {
      int j = i - 512;
      float v;
      if (j < 512) v = bk[j];
      else if (j < 1024) v = bv[j - 512];
      else v = bp1[j - 1024];
      biasKVP[j] = v;
    } else if (i < 2176) {
      biasO[i - 1664] = bo[i - 1664];
    }
  }
}

// ---------------------------------------------------------------------------
// Combined projection GEMM (Q and K/V/P in one grid) + fused pviol epilogue.
// BM=64 x BN=128 x BK=64, 8 K-steps, 4 waves.
// A: double-buffered global_load_lds (2 calls/wave/step), ONE barrier/step.
// B: weights are L2-resident (1.7MB shared by 576 blocks) -> register
//    fragments loaded DIRECTLY from global with one-step prefetch; no B LDS.
//    LDS 50K->17K lifts occupancy; barrier drain shrinks (2 gl2lds not 6).
// ---------------------------------------------------------------------------
__global__ __launch_bounds__(256) void gemm_proj_all(
    const u16* __restrict__ hTopt, const u16* __restrict__ hTsar,
    const u16* __restrict__ WqT, const u16* __restrict__ KVPW,
    const float* __restrict__ biasQ, const float* __restrict__ biasKVP,
    const float* __restrict__ Wp2, const float* __restrict__ bp2,
    u16* __restrict__ Qbuf, u16* __restrict__ KVPbuf,
    float* __restrict__ pviol)
{
  __shared__ __align__(16) u16 Al[2][64 * 64];    // 16 KB
  __shared__ float Pv[256];
  const int tid = threadIdx.x;
  const int w = tid >> 6, lane = tid & 63;
  const int lhi = lane >> 4, llo = lane & 15;

  const int nwg = 13 * 576;
  const int phys = blockIdx.y * 13 + blockIdx.x;
  const int logical = xcd_swz(phys, nwg);
  const int bx = logical % 13;
  const int y = logical / 13;

  const int bt = y / 9, stile = y - bt * 9;
  const int s0 = stile * 64;

  const bool isQ = (bx < 4);
  const int bxl = isQ ? bx : bx - 4;
  const int col0 = bxl * 128;
  const int NC = isQ ? 512 : 1152;
  const u16* Ab = (isQ ? hTopt : hTsar) + (size_t)bt * (576 * 512)
                  + (size_t)s0 * 512;
  const u16* Bb = (isQ ? WqT : KVPW) + (size_t)col0 * 512;
  const float* bias = isQ ? biasQ : biasKVP;
  u16* C = isQ ? Qbuf : KVPbuf;
  const bool dopv = (!isQ) && (bxl == 8);

  const int brow = lane >> 3;
  const int bko = ((lane & 7) ^ brow) * 8;

  // per-lane B row bases (two n rows) — data identical to the old LDS path
  const u16* Br0 = Bb + (size_t)(w * 32 + llo) * 512;        // ni=0
  const u16* Br1 = Bb + (size_t)(w * 32 + 16 + llo) * 512;   // ni=1

  f32x4 acc[4][2];
#pragma unroll
  for (int mi = 0; mi < 4; ++mi)
#pragma unroll
    for (int ni = 0; ni < 2; ++ni)
#pragma unroll
      for (int e = 0; e < 4; ++e) acc[mi][ni][e] = 0.f;

  // prologue: stage A(0); prefetch B(0) fragments to regs
#pragma unroll
  for (int i = 0; i < 2; ++i) {
    int q = w * 2 + i;
    gl2lds16(Ab + (size_t)(q * 8 + brow) * 512 + bko, &Al[0][q * 512]);
  }
  s16x8 bcur[4], bnxt[4];   // [hh*2+ni]
#pragma unroll
  for (int hh = 0; hh < 2; ++hh) {
    bcur[hh * 2 + 0] = *(const s16x8*)(Br0 + ((hh << 2) | lhi) * 8);
    bcur[hh * 2 + 1] = *(const s16x8*)(Br1 + ((hh << 2) | lhi) * 8);
  }

  for (int kt = 0; kt < 8; ++kt) {
    __syncthreads();  // A(kt) resident; prev compute LDS reads done
    if (kt < 7) {
      const int ktn = kt + 1;
#pragma unroll
      for (int i = 0; i < 2; ++i) {
        int q = w * 2 + i;
        gl2lds16(Ab + (size_t)(q * 8 + brow) * 512 + ktn * 64 + bko,
                 &Al[ktn & 1][q * 512]);
      }
#pragma unroll
      for (int hh = 0; hh < 2; ++hh) {
        bnxt[hh * 2 + 0] = *(const s16x8*)(Br0 + ktn * 64 + ((hh << 2) | lhi) * 8);
        bnxt[hh * 2 + 1] = *(const s16x8*)(Br1 + ktn * 64 + ((hh << 2) | lhi) * 8);
      }
    }
    const u16* Alc = Al[kt & 1];
#pragma unroll
    for (int hh = 0; hh < 2; ++hh) {
      s16x8 af[4];
#pragma unroll
      for (int mi = 0; mi < 4; ++mi) {
        int row = mi * 16 + llo;
        af[mi] = *(const s16x8*)&Alc[row * 64 + ((((hh << 2) | lhi) ^ (row & 7)) * 8)];
      }
#pragma unroll
      for (int mi = 0; mi < 4; ++mi) {
        acc[mi][0] = __builtin_amdgcn_mfma_f32_16x16x32_bf16(
            af[mi], bcur[hh * 2 + 0], acc[mi][0], 0, 0, 0);
        acc[mi][1] = __builtin_amdgcn_mfma_f32_16x16x32_bf16(
            af[mi], bcur[hh * 2 + 1], acc[mi][1], 0, 0, 0);
      }
    }
    if (kt < 7) {
#pragma unroll
      for (int j = 0; j < 4; ++j) bcur[j] = bnxt[j];
    }
  }

  const int b_ = bt >> 4, t_ = bt & 15;
  const size_t rowbase = (size_t)(b_ * 576 + s0) * 16 + t_;
  float bia0 = bias[col0 + w * 32 + llo];
  float bia1 = bias[col0 + w * 32 + 16 + llo];

  if (dopv) {
    const float w2a = Wp2[w * 32 + llo];
    const float w2b = Wp2[w * 32 + 16 + llo];
    float part[16];
#pragma unroll
    for (int mi = 0; mi < 4; ++mi)
#pragma unroll
      for (int i = 0; i < 4; ++i) {
        float x0 = acc[mi][0][i] + bia0;
        float x1 = acc[mi][1][i] + bia1;
        float g0 = 0.5f * x0 * (1.f + erff(x0 * 0.70710678f));
        float g1 = 0.5f * x1 * (1.f + erff(x1 * 0.70710678f));
        part[mi * 4 + i] = g0 * w2a + g1 * w2b;
      }
#pragma unroll
    for (int d = 1; d < 16; d <<= 1)
#pragma unroll
      for (int idx = 0; idx < 16; ++idx)
        part[idx] += __shfl_xor(part[idx], d, 64);
    if (llo == 0) {
#pragma unroll
      for (int mi = 0; mi < 4; ++mi)
#pragma unroll
        for (int i = 0; i < 4; ++i)
          Pv[w * 64 + mi * 16 + lhi * 4 + i] = part[mi * 4 + i];
    }
    __syncthreads();
    if (tid < 64) {
      float sum = Pv[tid] + Pv[64 + tid] + Pv[128 + tid] + Pv[192 + tid]
                  + bp2[0];
      pviol[rowbase + (size_t)tid * 16] = 1.f / (1.f + expf(-sum));
    }
  } else {
#pragma unroll
    for (int mi = 0; mi < 4; ++mi) {
#pragma unroll
      for (int i = 0; i < 4; ++i) {
        const int m = mi * 16 + lhi * 4 + i;
        u16* cp = C + (rowbase + (size_t)m * 16) * NC + col0 + w * 32 + llo;
        cp[0]  = f2bf(acc[mi][0][i] + bia0);
        cp[16] = f2bf(acc[mi][1][i] + bia1);
      }
    }
  }
}

// ---------------------------------------------------------------------------
// Attention, MFMA version (verified R8). One wave per (n, head); no barriers.
// ---------------------------------------------------------------------------
__global__ __launch_bounds__(256) void attn_kernel(
    const u16* Q, const u16* __restrict__ KVP,
    const float* __restrict__ pviol, u16* att)
{
  __shared__ __align__(16) u16 Vl[4][16 * 72];
  __shared__ __align__(16) u16 Ol[4][16 * 72];
  const int tid = threadIdx.x;
  const int w = tid >> 6, lane = tid & 63;
  const int logical = xcd_swz(blockIdx.x, gridDim.x);
  const int wid = logical * 4 + w;
  const int n = wid >> 3, hh = wid & 7;
  const int g = lane >> 4, llo = lane & 15;

  const int r = lane >> 3, co = (lane & 7) * 8;
  {
    const u16* Vb = KVP + (size_t)n * (16 * 1152) + 512 + hh * 64;
#pragma unroll
    for (int rr = 0; rr < 2; ++rr) {
      int row = r + rr * 8;
      *(u16x8*)&Vl[w][row * 72 + co] =
          *(const u16x8*)(Vb + (size_t)row * 1152 + co);
    }
  }

  const u16* Qr = Q + ((size_t)n * 16 + llo) * 512 + hh * 64;
  const u16* Kr = KVP + ((size_t)n * 16 + llo) * 1152 + hh * 64;
  s16x8 qa0 = *(const s16x8*)(Qr + g * 8);
  s16x8 qa1 = *(const s16x8*)(Qr + 32 + g * 8);
  s16x8 ka0 = *(const s16x8*)(Kr + g * 8);
  s16x8 ka1 = *(const s16x8*)(Kr + 32 + g * 8);

  f32x4 sacc = {0.f, 0.f, 0.f, 0.f};
  sacc = __builtin_amdgcn_mfma_f32_16x16x32_bf16(ka0, qa0, sacc, 0, 0, 0);
  sacc = __builtin_amdgcn_mfma_f32_16x16x32_bf16(ka1, qa1, sacc, 0, 0, 0);
  // lane(g,llo) holds S[llo][g*4+i]

  const float* pv = pviol + n * 16;
  float s[4];
#pragma unroll
  for (int i = 0; i < 4; ++i) s[i] = sacc[i] * 0.125f - GAMMA * pv[g * 4 + i];

  float mx = fmaxf(fmaxf(s[0], s[1]), fmaxf(s[2], s[3]));
  mx = fmaxf(mx, __shfl_xor(mx, 16, 64));
  mx = fmaxf(mx, __shfl_xor(mx, 32, 64));
  float e[4], sum = 0.f;
#pragma unroll
  for (int i = 0; i < 4; ++i) { e[i] = expf(s[i] - mx); sum += e[i]; }
  sum += __shfl_xor(sum, 16, 64);
  sum += __shfl_xor(sum, 32, 64);
  float inv = 1.f / sum;

  unsigned p01 = pk_bf16(e[0] * inv, e[1] * inv);
  unsigned p23 = pk_bf16(e[2] * inv, e[3] * inv);

  const int sa = ((2 * g) & 3) * 16 + llo;
  const int sb = ((2 * g + 1) & 3) * 16 + llo;
  unsigned a0 = (unsigned)__shfl((int)p01, sa, 64);
  unsigned a1 = (unsigned)__shfl((int)p23, sa, 64);
  unsigned b0 = (unsigned)__shfl((int)p01, sb, 64);
  unsigned b1 = (unsigned)__shfl((int)p23, sb, 64);
  ui32x4 afu = {0u, 0u, 0u, 0u};
  if (g < 2) { afu[0] = a0; afu[1] = a1; afu[2] = b0; afu[3] = b1; }
  s16x8 pfrag;
  __builtin_memcpy(&pfrag, &afu, 16);

  f32x4 oacc[4];
#pragma unroll
  for (int c = 0; c < 4; ++c) {
    u16 vb[8];
#pragma unroll
    for (int j = 0; j < 8; ++j)
      vb[j] = (g < 2) ? Vl[w][(g * 8 + j) * 72 + c * 16 + llo] : (u16)0;
    s16x8 vfrag;
    __builtin_memcpy(&vfrag, vb, 16);
    f32x4 z = {0.f, 0.f, 0.f, 0.f};
    oacc[c] = __builtin_amdgcn_mfma_f32_16x16x32_bf16(pfrag, vfrag, z, 0, 0, 0);
  }

#pragma unroll
  for (int c = 0; c < 4; ++c)
#pragma unroll
    for (int i = 0; i < 4; ++i)
      Ol[w][(g * 4 + i) * 72 + c * 16 + llo] = f2bf(oacc[c][i]);

  {
    u16* ob = att + ((size_t)n * 16) * 512 + hh * 64;
#pragma unroll
    for (int rr = 0; rr < 2; ++rr) {
      int row = r + rr * 8;
      *(u16x8*)(ob + (size_t)row * 512 + co) = *(const u16x8*)&Ol[w][row * 72 + co];
    }
  }
}

// ---------------------------------------------------------------------------
// Output projection: bf16 A (row-major, stride 16*512) x WoT.
// Verified double-buffered form (R3/R4/R5): ONE __syncthreads per K-step.
// ---------------------------------------------------------------------------
__global__ __launch_bounds__(256) void gemm_out(
    const u16* __restrict__ A, const u16* __restrict__ WT,
    const float* __restrict__ bias, float* __restrict__ out)
{
  __shared__ __align__(16) char smem[49152];       // Al(16K)+Bl(32K); Cl aliases
  u16* Al0 = (u16*)smem;                           // [2][64*64]
  u16* Bl0 = (u16*)(smem + 16384);                 // [2][128*64]
  const int tid = threadIdx.x;
  const int w = tid >> 6, lane = tid & 63;
  const int lhi = lane >> 4, llo = lane & 15;

  const int nwg = gridDim.x * gridDim.y;
  const int phys = blockIdx.y * gridDim.x + blockIdx.x;
  const int logical = xcd_swz(phys, nwg);
  const int bx = logical % gridDim.x;
  const int y = logical / gridDim.x;

  const int bt = y / 9, stile = y - bt * 9;
  const int s0 = stile * 64;
  const int col0 = bx * 128;
  const int b_ = bt >> 4, t_ = bt & 15;

  const u16* Ab = A + ((size_t)(b_ * 576 + s0) * 16 + t_) * 512;
  const u16* Bb = WT + (size_t)col0 * 512;

  const int brow = lane >> 3;
  const int bko = ((lane & 7) ^ brow) * 8;

  f32x4 acc[4][2];
#pragma unroll
  for (int mi = 0; mi < 4; ++mi)
#pragma unroll
    for (int ni = 0; ni < 2; ++ni)
#pragma unroll
      for (int e = 0; e < 4; ++e) acc[mi][ni][e] = 0.f;

  // prologue: stage tiles(0)
#pragma unroll
  for (int i = 0; i < 2; ++i) {
    int q = w * 2 + i;
    gl2lds16(Ab + (size_t)(q * 8 + brow) * (16 * 512) + bko, &Al0[q * 512]);
  }
#pragma unroll
  for (int i = 0; i < 4; ++i) {
    int q = w * 4 + i;
    gl2lds16(Bb + (size_t)(q * 8 + brow) * 512 + bko, &Bl0[q * 512]);
  }

  for (int kt = 0; kt < 8; ++kt) {
    __syncthreads();  // tiles(kt) resident; prev compute reads done
    if (kt < 7) {
      const int ktn = kt + 1;
      u16* Ala = Al0 + (ktn & 1) * (64 * 64);
      u16* Bla = Bl0 + (ktn & 1) * (128 * 64);
#pragma unroll
      for (int i = 0; i < 2; ++i) {
        int q = w * 2 + i;
        gl2lds16(Ab + (size_t)(q * 8 + brow) * (16 * 512) + ktn * 64 + bko,
                 &Ala[q * 512]);
      }
#pragma unroll
      for (int i = 0; i < 4; ++i) {
        int q = w * 4 + i;
        gl2lds16(Bb + (size_t)(q * 8 + brow) * 512 + ktn * 64 + bko,
                 &Bla[q * 512]);
      }
    }
    const u16* Alc = Al0 + (kt & 1) * (64 * 64);
    const u16* Blc = Bl0 + (kt & 1) * (128 * 64);
#pragma unroll
    for (int hh = 0; hh < 2; ++hh) {
      s16x8 af[4], bfr[2];
#pragma unroll
      for (int mi = 0; mi < 4; ++mi) {
        int row = mi * 16 + llo;
        af[mi] = *(const s16x8*)&Alc[row * 64 + ((((hh << 2) | lhi) ^ (row & 7)) * 8)];
      }
#pragma unroll
      for (int ni = 0; ni < 2; ++ni) {
        int n = w * 32 + ni * 16 + llo;
        bfr[ni] = *(const s16x8*)&Blc[n * 64 + ((((hh << 2) | lhi) ^ (n & 7)) * 8)];
      }
#pragma unroll
      for (int mi = 0; mi < 4; ++mi)
#pragma unroll
        for (int ni = 0; ni < 2; ++ni)
          acc[mi][ni] = __builtin_amdgcn_mfma_f32_16x16x32_bf16(
              af[mi], bfr[ni], acc[mi][ni], 0, 0, 0);
    }
  }

  __syncthreads();
  float* Cl = (float*)smem;  // 128 (n) x 72 (m, padded) fp32
  float bia0 = bias[col0 + w * 32 + llo];
  float bia1 = bias[col0 + w * 32 + 16 + llo];
#pragma unroll
  for (int mi = 0; mi < 4; ++mi)
#pragma unroll
    for (int i = 0; i < 4; ++i) {
      int m = mi * 16 + lhi * 4 + i;
      Cl[(w * 32 + llo) * 72 + m]      = acc[mi][0][i] + bia0;
      Cl[(w * 32 + 16 + llo) * 72 + m] = acc[mi][1][i] + bia1;
    }
  __syncthreads();
  const int nn = tid >> 1;
  const int mh = (tid & 1) * 32;
  const float* sp = Cl + nn * 72 + mh;
  float* dp = out + ((size_t)bt * 512 + col0 + nn) * 576 + s0 + mh;
#pragma unroll
  for (int j = 0; j < 8; ++j)
    *(float4*)(dp + j * 4) = *(const float4*)(sp + j * 4);
}

extern "C" void kernel_launch(void* const* d_in, const int* in_sizes, int n_in,
                              void* d_out, int out_size, void* d_ws, size_t ws_size,
                              hipStream_t stream)
{
  const float* h_opt = (const float*)d_in[0];
  const float* h_sar = (const float*)d_in[1];
  const float* Wq  = (const float*)d_in[2];
  const float* bq  = (const float*)d_in[3];
  const float* Wk  = (const float*)d_in[4];
  const float* bk  = (const float*)d_in[5];
  const float* Wv  = (const float*)d_in[6];
  const float* bv  = (const float*)d_in[7];
  const float* Wo  = (const float*)d_in[8];
  const float* bo  = (const float*)d_in[9];
  const float* Wp1 = (const float*)d_in[10];
  const float* bp1 = (const float*)d_in[11];
  const float* Wp2 = (const float*)d_in[12];
  const float* bp2 = (const float*)d_in[13];
  float* out = (float*)d_out;

  char* ws = (char*)d_ws;
  u16*   WqT     = (u16*)(ws + 0);          // 512x512 bf16   (524288 B)
  u16*   KVPW    = (u16*)(ws + 524288);     // 1152x512 bf16  (1179648 B)
  u16*   WoT     = (u16*)(ws + 1703936);    // 512x512 bf16   (524288 B)
  float* biasQ   = (float*)(ws + 2228224);  // 512 f32
  float* biasKVP = (float*)(ws + 2230272);  // 1152 f32
  float* biasO   = (float*)(ws + 2234880);  // 512 f32
  float* pviol   = (float*)(ws + 2236928);  // 36864 f32
  u16*   Qbuf    = (u16*)(ws + 2384384);    // 36864x512 bf16  — also att
  u16*   KVPbuf  = (u16*)(ws + 40133120);   // 36864x1152 bf16 (84934656 B)
  u16*   hTopt   = (u16*)(ws + 125067776);  // 64x576x512 bf16 (37748736 B)
  u16*   hTsar   = (u16*)(ws + 162816512);  // 64x576x512 bf16 (37748736 B)

  prep_all<<<PREP_NB, 256, 0, stream>>>(
      h_opt, h_sar, hTopt, hTsar, Wq, Wk, Wv, Wp1, Wo,
      bq, bk, bv, bp1, bo, WqT, KVPW, WoT, biasQ, biasKVP, biasO);

  gemm_proj_all<<<dim3(13, 576), 256, 0, stream>>>(
      hTopt, hTsar, WqT, KVPW, biasQ, biasKVP, Wp2, bp2,
      Qbuf, KVPbuf, pviol);

  attn_kernel<<<4608, 256, 0, stream>>>(Qbuf, KVPbuf, pviol, Qbuf);
  gemm_out<<<dim3(4, 576), 256, 0, stream>>>(Qbuf, WoT, biasO, out);
}

// Round 11
// 377.409 us; speedup vs baseline: 1.1062x; 1.1062x over previous
//
#include <hip/hip_runtime.h>

#define GAMMA 0.1f

typedef unsigned short u16;
typedef u16 u16x8 __attribute__((ext_vector_type(8)));
typedef short s16x8 __attribute__((ext_vector_type(8)));
typedef float f32x4 __attribute__((ext_vector_type(4)));
typedef unsigned int ui32x4 __attribute__((ext_vector_type(4)));
typedef unsigned int ui32x2 __attribute__((ext_vector_type(2)));

__device__ __forceinline__ float b2f(u16 u) {
  return __uint_as_float(((unsigned)u) << 16);
}
__device__ __forceinline__ u16 f2bf(float f) {
  unsigned u = __float_as_uint(f);
  unsigned r = (u + 0x7FFFu + ((u >> 16) & 1u)) >> 16;
  return (u16)r;
}
// pack two f32 -> one u32 holding (bf16(lo) | bf16(hi)<<16)
__device__ __forceinline__ unsigned pk_bf16(float lo, float hi) {
  return (unsigned)f2bf(lo) | ((unsigned)f2bf(hi) << 16);
}

// async global->LDS, 16B per lane; lds base must be wave-uniform, HW adds lane*16
__device__ __forceinline__ void gl2lds16(const u16* g, u16* l) {
  __builtin_amdgcn_global_load_lds(
      (const __attribute__((address_space(1))) unsigned int*)g,
      (__attribute__((address_space(3))) unsigned int*)l, 16, 0, 0);
}

// XCD-aware bijective swizzle (requires nwg % 8 == 0)
__device__ __forceinline__ int xcd_swz(int phys, int nwg) {
  return (phys & 7) * (nwg >> 3) + (phys >> 3);
}

// ---------------------------------------------------------------------------
// prep_all: one launch for all preprocessing.
// h-transpose now float4-vectorized: thread -> 4 s x 4 k; 4x fewer load
// instructions (16B/lane coalesced), same bytes, identical LDS/T layout.
// ---------------------------------------------------------------------------
#define PREP_NCONV 9216
#define PREP_T0 9216
#define PREP_T1 10240
#define PREP_T2 11264
#define PREP_T3 12288
#define PREP_T4 12544
#define PREP_T5 13568
#define PREP_NB 13577

__device__ __forceinline__ void tr_block(
    const float* __restrict__ src, u16* __restrict__ dst, int N, int blk, int tid)
{
  int idx = blk * 256 + tid;
  int nn = idx >> 9, kk = idx & 511;
  dst[idx] = f2bf(src[kk * N + nn]);
}

__global__ __launch_bounds__(256) void prep_all(
    const float* __restrict__ h0, const float* __restrict__ h1,
    u16* __restrict__ d0, u16* __restrict__ d1,
    const float* __restrict__ Wq, const float* __restrict__ Wk,
    const float* __restrict__ Wv, const float* __restrict__ Wp1,
    const float* __restrict__ Wo,
    const float* __restrict__ bq, const float* __restrict__ bk,
    const float* __restrict__ bv, const float* __restrict__ bp1,
    const float* __restrict__ bo,
    u16* __restrict__ WqT, u16* __restrict__ KVPW, u16* __restrict__ WoT,
    float* __restrict__ biasQ, float* __restrict__ biasKVP,
    float* __restrict__ biasO)
{
  __shared__ __align__(16) u16 T[64 * 64];
  const int b = blockIdx.x;
  const int tid = threadIdx.x;

  if (b < PREP_NCONV) {
    const int z = b / 4608;
    const int r_ = b - z * 4608;
    const int bt = r_ / 72;
    const int xx = r_ - bt * 72;
    const int kt = xx & 7, st = xx >> 3;
    const float* src = (z ? h1 : h0) + (size_t)bt * (512 * 576);
    u16* dst = (z ? d1 : d0) + (size_t)bt * (576 * 512);

    // thread -> s quad (tid&15)*4, k quad (tid>>4)*4
    const int s4 = (tid & 15) * 4;
    const int kq = (tid >> 4) * 4;
    const float* sp = src + (size_t)(kt * 64 + kq) * 576 + st * 64 + s4;
    float4 f0 = *(const float4*)(sp);
    float4 f1 = *(const float4*)(sp + 576);
    float4 f2 = *(const float4*)(sp + 1152);
    float4 f3 = *(const float4*)(sp + 1728);
    const int oc = kq >> 3;            // octet index
    const int half = (kq >> 2) & 1;    // which half of the octet
    float a0[4] = {f0.x, f0.y, f0.z, f0.w};
    float a1[4] = {f1.x, f1.y, f1.z, f1.w};
    float a2[4] = {f2.x, f2.y, f2.z, f2.w};
    float a3[4] = {f3.x, f3.y, f3.z, f3.w};
#pragma unroll
    for (int i = 0; i < 4; ++i) {
      int s = s4 + i;
      ui32x2 q = {pk_bf16(a0[i], a1[i]), pk_bf16(a2[i], a3[i])};
      *(ui32x2*)&T[s * 64 + ((oc ^ (s & 7)) * 8) + half * 4] = q;
    }
    __syncthreads();
    const int r = tid >> 2, oc2 = (tid & 3) * 2;
    ui32x4 w0 = *(const ui32x4*)&T[r * 64 + ((oc2       ^ (r & 7)) * 8)];
    ui32x4 w1 = *(const ui32x4*)&T[r * 64 + (((oc2 + 1) ^ (r & 7)) * 8)];
    u16* dp = dst + (size_t)(st * 64 + r) * 512 + kt * 64 + oc2 * 8;
    *(ui32x4*)dp = w0;
    *(ui32x4*)(dp + 8) = w1;
  } else if (b < PREP_T1) {
    tr_block(Wq, WqT, 512, b - PREP_T0, tid);
  } else if (b < PREP_T2) {
    tr_block(Wk, KVPW, 512, b - PREP_T1, tid);
  } else if (b < PREP_T3) {
    tr_block(Wv, KVPW + 512 * 512, 512, b - PREP_T2, tid);
  } else if (b < PREP_T4) {
    tr_block(Wp1, KVPW + 1024 * 512, 128, b - PREP_T3, tid);
  } else if (b < PREP_T5) {
    tr_block(Wo, WoT, 512, b - PREP_T4, tid);
  } else {
    int i = (b - PREP_T5) * 256 + tid;
    if (i < 512) {
      biasQ[i] = bq[i];
    } else if (i < 1664) {
      int j = i - 512;
      float v;
      if (j < 512) v = bk[j];
      else if (j < 1024) v = bv[j - 512];
      else v = bp1[j - 1024];
      biasKVP[j] = v;
    } else if (i < 2176) {
      biasO[i - 1664] = bo[i - 1664];
    }
  }
}

// ---------------------------------------------------------------------------
// Combined projection GEMM (Q and K/V/P in one grid) + fused pviol epilogue.
// BM=64 x BN=128 x BK=64, 8 K-steps, 4 waves; double-buffered global_load_lds
// with pre-swizzled source; ONE __syncthreads per K-step (verified R8, 115us).
// ---------------------------------------------------------------------------
__global__ __launch_bounds__(256) void gemm_proj_all(
    const u16* __restrict__ hTopt, const u16* __restrict__ hTsar,
    const u16* __restrict__ WqT, const u16* __restrict__ KVPW,
    const float* __restrict__ biasQ, const float* __restrict__ biasKVP,
    const float* __restrict__ Wp2, const float* __restrict__ bp2,
    u16* __restrict__ Qbuf, u16* __restrict__ KVPbuf,
    float* __restrict__ pviol)
{
  __shared__ __align__(16) u16 Al[2][64 * 64];    // 16 KB
  __shared__ __align__(16) u16 Bl[2][128 * 64];   // 32 KB
  __shared__ float Pv[256];
  const int tid = threadIdx.x;
  const int w = tid >> 6, lane = tid & 63;
  const int lhi = lane >> 4, llo = lane & 15;

  const int nwg = 13 * 576;
  const int phys = blockIdx.y * 13 + blockIdx.x;
  const int logical = xcd_swz(phys, nwg);
  const int bx = logical % 13;
  const int y = logical / 13;

  const int bt = y / 9, stile = y - bt * 9;
  const int s0 = stile * 64;

  const bool isQ = (bx < 4);
  const int bxl = isQ ? bx : bx - 4;
  const int col0 = bxl * 128;
  const int NC = isQ ? 512 : 1152;
  const u16* Ab = (isQ ? hTopt : hTsar) + (size_t)bt * (576 * 512)
                  + (size_t)s0 * 512;
  const u16* Bb = (isQ ? WqT : KVPW) + (size_t)col0 * 512;
  const float* bias = isQ ? biasQ : biasKVP;
  u16* C = isQ ? Qbuf : KVPbuf;
  const bool dopv = (!isQ) && (bxl == 8);

  const int brow = lane >> 3;
  const int bko = ((lane & 7) ^ brow) * 8;

  f32x4 acc[4][2];
#pragma unroll
  for (int mi = 0; mi < 4; ++mi)
#pragma unroll
    for (int ni = 0; ni < 2; ++ni)
#pragma unroll
      for (int e = 0; e < 4; ++e) acc[mi][ni][e] = 0.f;

  // prologue: stage tiles(0)
#pragma unroll
  for (int i = 0; i < 2; ++i) {
    int q = w * 2 + i;
    gl2lds16(Ab + (size_t)(q * 8 + brow) * 512 + bko, &Al[0][q * 512]);
  }
#pragma unroll
  for (int i = 0; i < 4; ++i) {
    int q = w * 4 + i;
    gl2lds16(Bb + (size_t)(q * 8 + brow) * 512 + bko, &Bl[0][q * 512]);
  }

  for (int kt = 0; kt < 8; ++kt) {
    __syncthreads();  // tiles(kt) resident; prev compute reads done
    if (kt < 7) {
      const int ktn = kt + 1;
#pragma unroll
      for (int i = 0; i < 2; ++i) {
        int q = w * 2 + i;
        gl2lds16(Ab + (size_t)(q * 8 + brow) * 512 + ktn * 64 + bko,
                 &Al[ktn & 1][q * 512]);
      }
#pragma unroll
      for (int i = 0; i < 4; ++i) {
        int q = w * 4 + i;
        gl2lds16(Bb + (size_t)(q * 8 + brow) * 512 + ktn * 64 + bko,
                 &Bl[ktn & 1][q * 512]);
      }
    }
    const u16* Alc = Al[kt & 1];
    const u16* Blc = Bl[kt & 1];
#pragma unroll
    for (int hh = 0; hh < 2; ++hh) {
      s16x8 af[4], bfr[2];
#pragma unroll
      for (int mi = 0; mi < 4; ++mi) {
        int row = mi * 16 + llo;
        af[mi] = *(const s16x8*)&Alc[row * 64 + ((((hh << 2) | lhi) ^ (row & 7)) * 8)];
      }
#pragma unroll
      for (int ni = 0; ni < 2; ++ni) {
        int n = w * 32 + ni * 16 + llo;
        bfr[ni] = *(const s16x8*)&Blc[n * 64 + ((((hh << 2) | lhi) ^ (n & 7)) * 8)];
      }
#pragma unroll
      for (int mi = 0; mi < 4; ++mi)
#pragma unroll
        for (int ni = 0; ni < 2; ++ni)
          acc[mi][ni] = __builtin_amdgcn_mfma_f32_16x16x32_bf16(
              af[mi], bfr[ni], acc[mi][ni], 0, 0, 0);
    }
  }

  const int b_ = bt >> 4, t_ = bt & 15;
  const size_t rowbase = (size_t)(b_ * 576 + s0) * 16 + t_;
  float bia0 = bias[col0 + w * 32 + llo];
  float bia1 = bias[col0 + w * 32 + 16 + llo];

  if (dopv) {
    const float w2a = Wp2[w * 32 + llo];
    const float w2b = Wp2[w * 32 + 16 + llo];
    float part[16];
#pragma unroll
    for (int mi = 0; mi < 4; ++mi)
#pragma unroll
      for (int i = 0; i < 4; ++i) {
        float x0 = acc[mi][0][i] + bia0;
        float x1 = acc[mi][1][i] + bia1;
        float g0 = 0.5f * x0 * (1.f + erff(x0 * 0.70710678f));
        float g1 = 0.5f * x1 * (1.f + erff(x1 * 0.70710678f));
        part[mi * 4 + i] = g0 * w2a + g1 * w2b;
      }
#pragma unroll
    for (int d = 1; d < 16; d <<= 1)
#pragma unroll
      for (int idx = 0; idx < 16; ++idx)
        part[idx] += __shfl_xor(part[idx], d, 64);
    if (llo == 0) {
#pragma unroll
      for (int mi = 0; mi < 4; ++mi)
#pragma unroll
        for (int i = 0; i < 4; ++i)
          Pv[w * 64 + mi * 16 + lhi * 4 + i] = part[mi * 4 + i];
    }
    __syncthreads();
    if (tid < 64) {
      float sum = Pv[tid] + Pv[64 + tid] + Pv[128 + tid] + Pv[192 + tid]
                  + bp2[0];
      pviol[rowbase + (size_t)tid * 16] = 1.f / (1.f + expf(-sum));
    }
  } else {
#pragma unroll
    for (int mi = 0; mi < 4; ++mi) {
#pragma unroll
      for (int i = 0; i < 4; ++i) {
        const int m = mi * 16 + lhi * 4 + i;
        u16* cp = C + (rowbase + (size_t)m * 16) * NC + col0 + w * 32 + llo;
        cp[0]  = f2bf(acc[mi][0][i] + bia0);
        cp[16] = f2bf(acc[mi][1][i] + bia1);
      }
    }
  }
}

// ---------------------------------------------------------------------------
// Attention, MFMA version (verified R8). One wave per (n, head); no barriers.
// ---------------------------------------------------------------------------
__global__ __launch_bounds__(256) void attn_kernel(
    const u16* Q, const u16* __restrict__ KVP,
    const float* __restrict__ pviol, u16* att)
{
  __shared__ __align__(16) u16 Vl[4][16 * 72];
  __shared__ __align__(16) u16 Ol[4][16 * 72];
  const int tid = threadIdx.x;
  const int w = tid >> 6, lane = tid & 63;
  const int logical = xcd_swz(blockIdx.x, gridDim.x);
  const int wid = logical * 4 + w;
  const int n = wid >> 3, hh = wid & 7;
  const int g = lane >> 4, llo = lane & 15;

  const int r = lane >> 3, co = (lane & 7) * 8;
  {
    const u16* Vb = KVP + (size_t)n * (16 * 1152) + 512 + hh * 64;
#pragma unroll
    for (int rr = 0; rr < 2; ++rr) {
      int row = r + rr * 8;
      *(u16x8*)&Vl[w][row * 72 + co] =
          *(const u16x8*)(Vb + (size_t)row * 1152 + co);
    }
  }

  const u16* Qr = Q + ((size_t)n * 16 + llo) * 512 + hh * 64;
  const u16* Kr = KVP + ((size_t)n * 16 + llo) * 1152 + hh * 64;
  s16x8 qa0 = *(const s16x8*)(Qr + g * 8);
  s16x8 qa1 = *(const s16x8*)(Qr + 32 + g * 8);
  s16x8 ka0 = *(const s16x8*)(Kr + g * 8);
  s16x8 ka1 = *(const s16x8*)(Kr + 32 + g * 8);

  f32x4 sacc = {0.f, 0.f, 0.f, 0.f};
  sacc = __builtin_amdgcn_mfma_f32_16x16x32_bf16(ka0, qa0, sacc, 0, 0, 0);
  sacc = __builtin_amdgcn_mfma_f32_16x16x32_bf16(ka1, qa1, sacc, 0, 0, 0);
  // lane(g,llo) holds S[llo][g*4+i]

  const float* pv = pviol + n * 16;
  float s[4];
#pragma unroll
  for (int i = 0; i < 4; ++i) s[i] = sacc[i] * 0.125f - GAMMA * pv[g * 4 + i];

  float mx = fmaxf(fmaxf(s[0], s[1]), fmaxf(s[2], s[3]));
  mx = fmaxf(mx, __shfl_xor(mx, 16, 64));
  mx = fmaxf(mx, __shfl_xor(mx, 32, 64));
  float e[4], sum = 0.f;
#pragma unroll
  for (int i = 0; i < 4; ++i) { e[i] = expf(s[i] - mx); sum += e[i]; }
  sum += __shfl_xor(sum, 16, 64);
  sum += __shfl_xor(sum, 32, 64);
  float inv = 1.f / sum;

  unsigned p01 = pk_bf16(e[0] * inv, e[1] * inv);
  unsigned p23 = pk_bf16(e[2] * inv, e[3] * inv);

  const int sa = ((2 * g) & 3) * 16 + llo;
  const int sb = ((2 * g + 1) & 3) * 16 + llo;
  unsigned a0 = (unsigned)__shfl((int)p01, sa, 64);
  unsigned a1 = (unsigned)__shfl((int)p23, sa, 64);
  unsigned b0 = (unsigned)__shfl((int)p01, sb, 64);
  unsigned b1 = (unsigned)__shfl((int)p23, sb, 64);
  ui32x4 afu = {0u, 0u, 0u, 0u};
  if (g < 2) { afu[0] = a0; afu[1] = a1; afu[2] = b0; afu[3] = b1; }
  s16x8 pfrag;
  __builtin_memcpy(&pfrag, &afu, 16);

  f32x4 oacc[4];
#pragma unroll
  for (int c = 0; c < 4; ++c) {
    u16 vb[8];
#pragma unroll
    for (int j = 0; j < 8; ++j)
      vb[j] = (g < 2) ? Vl[w][(g * 8 + j) * 72 + c * 16 + llo] : (u16)0;
    s16x8 vfrag;
    __builtin_memcpy(&vfrag, vb, 16);
    f32x4 z = {0.f, 0.f, 0.f, 0.f};
    oacc[c] = __builtin_amdgcn_mfma_f32_16x16x32_bf16(pfrag, vfrag, z, 0, 0, 0);
  }

#pragma unroll
  for (int c = 0; c < 4; ++c)
#pragma unroll
    for (int i = 0; i < 4; ++i)
      Ol[w][(g * 4 + i) * 72 + c * 16 + llo] = f2bf(oacc[c][i]);

  {
    u16* ob = att + ((size_t)n * 16) * 512 + hh * 64;
#pragma unroll
    for (int rr = 0; rr < 2; ++rr) {
      int row = r + rr * 8;
      *(u16x8*)(ob + (size_t)row * 512 + co) = *(const u16x8*)&Ol[w][row * 72 + co];
    }
  }
}

// ---------------------------------------------------------------------------
// Output projection: bf16 A (row-major, stride 16*512) x WoT.
// Verified double-buffered form (R3/R4/R5): ONE __syncthreads per K-step.
// ---------------------------------------------------------------------------
__global__ __launch_bounds__(256) void gemm_out(
    const u16* __restrict__ A, const u16* __restrict__ WT,
    const float* __restrict__ bias, float* __restrict__ out)
{
  __shared__ __align__(16) char smem[49152];       // Al(16K)+Bl(32K); Cl aliases
  u16* Al0 = (u16*)smem;                           // [2][64*64]
  u16* Bl0 = (u16*)(smem + 16384);                 // [2][128*64]
  const int tid = threadIdx.x;
  const int w = tid >> 6, lane = tid & 63;
  const int lhi = lane >> 4, llo = lane & 15;

  const int nwg = gridDim.x * gridDim.y;
  const int phys = blockIdx.y * gridDim.x + blockIdx.x;
  const int logical = xcd_swz(phys, nwg);
  const int bx = logical % gridDim.x;
  const int y = logical / gridDim.x;

  const int bt = y / 9, stile = y - bt * 9;
  const int s0 = stile * 64;
  const int col0 = bx * 128;
  const int b_ = bt >> 4, t_ = bt & 15;

  const u16* Ab = A + ((size_t)(b_ * 576 + s0) * 16 + t_) * 512;
  const u16* Bb = WT + (size_t)col0 * 512;

  const int brow = lane >> 3;
  const int bko = ((lane & 7) ^ brow) * 8;

  f32x4 acc[4][2];
#pragma unroll
  for (int mi = 0; mi < 4; ++mi)
#pragma unroll
    for (int ni = 0; ni < 2; ++ni)
#pragma unroll
      for (int e = 0; e < 4; ++e) acc[mi][ni][e] = 0.f;

  // prologue: stage tiles(0)
#pragma unroll
  for (int i = 0; i < 2; ++i) {
    int q = w * 2 + i;
    gl2lds16(Ab + (size_t)(q * 8 + brow) * (16 * 512) + bko, &Al0[q * 512]);
  }
#pragma unroll
  for (int i = 0; i < 4; ++i) {
    int q = w * 4 + i;
    gl2lds16(Bb + (size_t)(q * 8 + brow) * 512 + bko, &Bl0[q * 512]);
  }

  for (int kt = 0; kt < 8; ++kt) {
    __syncthreads();  // tiles(kt) resident; prev compute reads done
    if (kt < 7) {
      const int ktn = kt + 1;
      u16* Ala = Al0 + (ktn & 1) * (64 * 64);
      u16* Bla = Bl0 + (ktn & 1) * (128 * 64);
#pragma unroll
      for (int i = 0; i < 2; ++i) {
        int q = w * 2 + i;
        gl2lds16(Ab + (size_t)(q * 8 + brow) * (16 * 512) + ktn * 64 + bko,
                 &Ala[q * 512]);
      }
#pragma unroll
      for (int i = 0; i < 4; ++i) {
        int q = w * 4 + i;
        gl2lds16(Bb + (size_t)(q * 8 + brow) * 512 + ktn * 64 + bko,
                 &Bla[q * 512]);
      }
    }
    const u16* Alc = Al0 + (kt & 1) * (64 * 64);
    const u16* Blc = Bl0 + (kt & 1) * (128 * 64);
#pragma unroll
    for (int hh = 0; hh < 2; ++hh) {
      s16x8 af[4], bfr[2];
#pragma unroll
      for (int mi = 0; mi < 4; ++mi) {
        int row = mi * 16 + llo;
        af[mi] = *(const s16x8*)&Alc[row * 64 + ((((hh << 2) | lhi) ^ (row & 7)) * 8)];
      }
#pragma unroll
      for (int ni = 0; ni < 2; ++ni) {
        int n = w * 32 + ni * 16 + llo;
        bfr[ni] = *(const s16x8*)&Blc[n * 64 + ((((hh << 2) | lhi) ^ (n & 7)) * 8)];
      }
#pragma unroll
      for (int mi = 0; mi < 4; ++mi)
#pragma unroll
        for (int ni = 0; ni < 2; ++ni)
          acc[mi][ni] = __builtin_amdgcn_mfma_f32_16x16x32_bf16(
              af[mi], bfr[ni], acc[mi][ni], 0, 0, 0);
    }
  }

  __syncthreads();
  float* Cl = (float*)smem;  // 128 (n) x 72 (m, padded) fp32
  float bia0 = bias[col0 + w * 32 + llo];
  float bia1 = bias[col0 + w * 32 + 16 + llo];
#pragma unroll
  for (int mi = 0; mi < 4; ++mi)
#pragma unroll
    for (int i = 0; i < 4; ++i) {
      int m = mi * 16 + lhi * 4 + i;
      Cl[(w * 32 + llo) * 72 + m]      = acc[mi][0][i] + bia0;
      Cl[(w * 32 + 16 + llo) * 72 + m] = acc[mi][1][i] + bia1;
    }
  __syncthreads();
  const int nn = tid >> 1;
  const int mh = (tid & 1) * 32;
  const float* sp = Cl + nn * 72 + mh;
  float* dp = out + ((size_t)bt * 512 + col0 + nn) * 576 + s0 + mh;
#pragma unroll
  for (int j = 0; j < 8; ++j)
    *(float4*)(dp + j * 4) = *(const float4*)(sp + j * 4);
}

extern "C" void kernel_launch(void* const* d_in, const int* in_sizes, int n_in,
                              void* d_out, int out_size, void* d_ws, size_t ws_size,
                              hipStream_t stream)
{
  const float* h_opt = (const float*)d_in[0];
  const float* h_sar = (const float*)d_in[1];
  const float* Wq  = (const float*)d_in[2];
  const float* bq  = (const float*)d_in[3];
  const float* Wk  = (const float*)d_in[4];
  const float* bk  = (const float*)d_in[5];
  const float* Wv  = (const float*)d_in[6];
  const float* bv  = (const float*)d_in[7];
  const float* Wo  = (const float*)d_in[8];
  const float* bo  = (const float*)d_in[9];
  const float* Wp1 = (const float*)d_in[10];
  const float* bp1 = (const float*)d_in[11];
  const float* Wp2 = (const float*)d_in[12];
  const float* bp2 = (const float*)d_in[13];
  float* out = (float*)d_out;

  char* ws = (char*)d_ws;
  u16*   WqT     = (u16*)(ws + 0);          // 512x512 bf16   (524288 B)
  u16*   KVPW    = (u16*)(ws + 524288);     // 1152x512 bf16  (1179648 B)
  u16*   WoT     = (u16*)(ws + 1703936);    // 512x512 bf16   (524288 B)
  float* biasQ   = (float*)(ws + 2228224);  // 512 f32
  float* biasKVP = (float*)(ws + 2230272);  // 1152 f32
  float* biasO   = (float*)(ws + 2234880);  // 512 f32
  float* pviol   = (float*)(ws + 2236928);  // 36864 f32
  u16*   Qbuf    = (u16*)(ws + 2384384);    // 36864x512 bf16  — also att
  u16*   KVPbuf  = (u16*)(ws + 40133120);   // 36864x1152 bf16 (84934656 B)
  u16*   hTopt   = (u16*)(ws + 125067776);  // 64x576x512 bf16 (37748736 B)
  u16*   hTsar   = (u16*)(ws + 162816512);  // 64x576x512 bf16 (37748736 B)

  prep_all<<<PREP_NB, 256, 0, stream>>>(
      h_opt, h_sar, hTopt, hTsar, Wq, Wk, Wv, Wp1, Wo,
      bq, bk, bv, bp1, bo, WqT, KVPW, WoT, biasQ, biasKVP, biasO);

  gemm_proj_all<<<dim3(13, 576), 256, 0, stream>>>(
      hTopt, hTsar, WqT, KVPW, biasQ, biasKVP, Wp2, bp2,
      Qbuf, KVPbuf, pviol);

  attn_kernel<<<4608, 256, 0, stream>>>(Qbuf, KVPbuf, pviol, Qbuf);
  gemm_out<<<dim3(4, 576), 256, 0, stream>>>(Qbuf, WoT, biasO, out);
}

// Round 12
// 359.991 us; speedup vs baseline: 1.1597x; 1.0484x over previous
//
#include <hip/hip_runtime.h>

#define GAMMA 0.1f

typedef unsigned short u16;
typedef u16 u16x8 __attribute__((ext_vector_type(8)));
typedef short s16x8 __attribute__((ext_vector_type(8)));
typedef float f32x4 __attribute__((ext_vector_type(4)));
typedef unsigned int ui32x4 __attribute__((ext_vector_type(4)));
typedef unsigned int ui32x2 __attribute__((ext_vector_type(2)));

__device__ __forceinline__ float b2f(u16 u) {
  return __uint_as_float(((unsigned)u) << 16);
}
__device__ __forceinline__ u16 f2bf(float f) {
  unsigned u = __float_as_uint(f);
  unsigned r = (u + 0x7FFFu + ((u >> 16) & 1u)) >> 16;
  return (u16)r;
}
// pack two f32 -> one u32 holding (bf16(lo) | bf16(hi)<<16)
__device__ __forceinline__ unsigned pk_bf16(float lo, float hi) {
  return (unsigned)f2bf(lo) | ((unsigned)f2bf(hi) << 16);
}

// async global->LDS, 16B per lane; lds base must be wave-uniform, HW adds lane*16
__device__ __forceinline__ void gl2lds16(const u16* g, u16* l) {
  __builtin_amdgcn_global_load_lds(
      (const __attribute__((address_space(1))) unsigned int*)g,
      (__attribute__((address_space(3))) unsigned int*)l, 16, 0, 0);
}

// XCD-aware bijective swizzle (requires nwg % 8 == 0)
__device__ __forceinline__ int xcd_swz(int phys, int nwg) {
  return (phys & 7) * (nwg >> 3) + (phys >> 3);
}

// ---------------------------------------------------------------------------
// prep_all: one launch for all preprocessing (R11-verified, float4 h-transpose)
// ---------------------------------------------------------------------------
#define PREP_NCONV 9216
#define PREP_T0 9216
#define PREP_T1 10240
#define PREP_T2 11264
#define PREP_T3 12288
#define PREP_T4 12544
#define PREP_T5 13568
#define PREP_NB 13577

__device__ __forceinline__ void tr_block(
    const float* __restrict__ src, u16* __restrict__ dst, int N, int blk, int tid)
{
  int idx = blk * 256 + tid;
  int nn = idx >> 9, kk = idx & 511;
  dst[idx] = f2bf(src[kk * N + nn]);
}

__global__ __launch_bounds__(256) void prep_all(
    const float* __restrict__ h0, const float* __restrict__ h1,
    u16* __restrict__ d0, u16* __restrict__ d1,
    const float* __restrict__ Wq, const float* __restrict__ Wk,
    const float* __restrict__ Wv, const float* __restrict__ Wp1,
    const float* __restrict__ Wo,
    const float* __restrict__ bq, const float* __restrict__ bk,
    const float* __restrict__ bv, const float* __restrict__ bp1,
    const float* __restrict__ bo,
    u16* __restrict__ WqT, u16* __restrict__ KVPW, u16* __restrict__ WoT,
    float* __restrict__ biasQ, float* __restrict__ biasKVP,
    float* __restrict__ biasO)
{
  __shared__ __align__(16) u16 T[64 * 64];
  const int b = blockIdx.x;
  const int tid = threadIdx.x;

  if (b < PREP_NCONV) {
    const int z = b / 4608;
    const int r_ = b - z * 4608;
    const int bt = r_ / 72;
    const int xx = r_ - bt * 72;
    const int kt = xx & 7, st = xx >> 3;
    const float* src = (z ? h1 : h0) + (size_t)bt * (512 * 576);
    u16* dst = (z ? d1 : d0) + (size_t)bt * (576 * 512);

    const int s4 = (tid & 15) * 4;
    const int kq = (tid >> 4) * 4;
    const float* sp = src + (size_t)(kt * 64 + kq) * 576 + st * 64 + s4;
    float4 f0 = *(const float4*)(sp);
    float4 f1 = *(const float4*)(sp + 576);
    float4 f2 = *(const float4*)(sp + 1152);
    float4 f3 = *(const float4*)(sp + 1728);
    const int oc = kq >> 3;
    const int half = (kq >> 2) & 1;
    float a0[4] = {f0.x, f0.y, f0.z, f0.w};
    float a1[4] = {f1.x, f1.y, f1.z, f1.w};
    float a2[4] = {f2.x, f2.y, f2.z, f2.w};
    float a3[4] = {f3.x, f3.y, f3.z, f3.w};
#pragma unroll
    for (int i = 0; i < 4; ++i) {
      int s = s4 + i;
      ui32x2 q = {pk_bf16(a0[i], a1[i]), pk_bf16(a2[i], a3[i])};
      *(ui32x2*)&T[s * 64 + ((oc ^ (s & 7)) * 8) + half * 4] = q;
    }
    __syncthreads();
    const int r = tid >> 2, oc2 = (tid & 3) * 2;
    ui32x4 w0 = *(const ui32x4*)&T[r * 64 + ((oc2       ^ (r & 7)) * 8)];
    ui32x4 w1 = *(const ui32x4*)&T[r * 64 + (((oc2 + 1) ^ (r & 7)) * 8)];
    u16* dp = dst + (size_t)(st * 64 + r) * 512 + kt * 64 + oc2 * 8;
    *(ui32x4*)dp = w0;
    *(ui32x4*)(dp + 8) = w1;
  } else if (b < PREP_T1) {
    tr_block(Wq, WqT, 512, b - PREP_T0, tid);
  } else if (b < PREP_T2) {
    tr_block(Wk, KVPW, 512, b - PREP_T1, tid);
  } else if (b < PREP_T3) {
    tr_block(Wv, KVPW + 512 * 512, 512, b - PREP_T2, tid);
  } else if (b < PREP_T4) {
    tr_block(Wp1, KVPW + 1024 * 512, 128, b - PREP_T3, tid);
  } else if (b < PREP_T5) {
    tr_block(Wo, WoT, 512, b - PREP_T4, tid);
  } else {
    int i = (b - PREP_T5) * 256 + tid;
    if (i < 512) {
      biasQ[i] = bq[i];
    } else if (i < 1664) {
      int j = i - 512;
      float v;
      if (j < 512) v = bk[j];
      else if (j < 1024) v = bv[j - 512];
      else v = bp1[j - 1024];
      biasKVP[j] = v;
    } else if (i < 2176) {
      biasO[i - 1664] = bo[i - 1664];
    }
  }
}

// ---------------------------------------------------------------------------
// Combined projection GEMM (Q and K/V/P) + fused pviol epilogue.
// 512 threads (8 waves). Tile: BM=128 rows (2 bt x 64 s) x BN=128 x BK=64.
// Wave (wr=w>>1, wc=w&1): 32 rows x 64 cols, acc[2][4] (32 VGPR) — per-wave
// MFMA density unchanged vs R8; gl2lds 6->4 per wave-step. LDS 65K ->
// 2 blocks x 8 waves = 16 waves/CU (vs 12): occupancy-driven stall hiding.
// Same verified ONE-__syncthreads-per-step double-buffer schedule.
// ---------------------------------------------------------------------------
__global__ __launch_bounds__(512) void gemm_proj_all(
    const u16* __restrict__ hTopt, const u16* __restrict__ hTsar,
    const u16* __restrict__ WqT, const u16* __restrict__ KVPW,
    const float* __restrict__ biasQ, const float* __restrict__ biasKVP,
    const float* __restrict__ Wp2, const float* __restrict__ bp2,
    u16* __restrict__ Qbuf, u16* __restrict__ KVPbuf,
    float* __restrict__ pviol)
{
  __shared__ __align__(16) u16 Al[2][128 * 64];   // 32 KB
  __shared__ __align__(16) u16 Bl[2][128 * 64];   // 32 KB
  __shared__ float Pv[2][128];                    // 1 KB
  const int tid = threadIdx.x;
  const int w = tid >> 6, lane = tid & 63;
  const int lhi = lane >> 4, llo = lane & 15;
  const int wr = w >> 1, wc = w & 1;

  const int nwg = 13 * 288;
  const int phys = blockIdx.y * 13 + blockIdx.x;
  const int logical = xcd_swz(phys, nwg);
  const int bx = logical % 13;
  const int y = logical / 13;

  const int btp = y / 9, stile = y - btp * 9;
  const int bt0 = btp * 2;                 // rows 0..63 -> bt0, 64..127 -> bt0+1
  const int s0 = stile * 64;

  const bool isQ = (bx < 4);
  const int bxl = isQ ? bx : bx - 4;
  const int col0 = bxl * 128;
  const int NC = isQ ? 512 : 1152;
  const u16* hT = isQ ? hTopt : hTsar;
  const u16* Ab0 = hT + (size_t)bt0 * (576 * 512) + (size_t)s0 * 512;
  const u16* Ab1 = Ab0 + (size_t)(576 * 512);
  const u16* Bb = (isQ ? WqT : KVPW) + (size_t)col0 * 512;
  const float* bias = isQ ? biasQ : biasKVP;
  u16* C = isQ ? Qbuf : KVPbuf;
  const bool dopv = (!isQ) && (bxl == 8);

  const int brow = lane >> 3;
  const int bko = ((lane & 7) ^ brow) * 8;

  f32x4 acc[2][4];
#pragma unroll
  for (int mi = 0; mi < 2; ++mi)
#pragma unroll
    for (int ni = 0; ni < 4; ++ni)
#pragma unroll
      for (int e = 0; e < 4; ++e) acc[mi][ni][e] = 0.f;

  // prologue: stage tiles(0). A: 16 calls (q=w*2+i), rows q*8..q*8+7.
#pragma unroll
  for (int i = 0; i < 2; ++i) {
    int q = w * 2 + i;
    const u16* Abase = (q < 8 ? Ab0 : Ab1) + (size_t)((q & 7) * 8 + brow) * 512;
    gl2lds16(Abase + bko, &Al[0][q * 512]);
  }
#pragma unroll
  for (int i = 0; i < 2; ++i) {
    int q = w * 2 + i;
    gl2lds16(Bb + (size_t)(q * 8 + brow) * 512 + bko, &Bl[0][q * 512]);
  }

  for (int kt = 0; kt < 8; ++kt) {
    __syncthreads();  // tiles(kt) resident; prev compute reads done
    if (kt < 7) {
      const int ktn = kt + 1;
#pragma unroll
      for (int i = 0; i < 2; ++i) {
        int q = w * 2 + i;
        const u16* Abase = (q < 8 ? Ab0 : Ab1) + (size_t)((q & 7) * 8 + brow) * 512;
        gl2lds16(Abase + ktn * 64 + bko, &Al[ktn & 1][q * 512]);
      }
#pragma unroll
      for (int i = 0; i < 2; ++i) {
        int q = w * 2 + i;
        gl2lds16(Bb + (size_t)(q * 8 + brow) * 512 + ktn * 64 + bko,
                 &Bl[ktn & 1][q * 512]);
      }
    }
    const u16* Alc = Al[kt & 1];
    const u16* Blc = Bl[kt & 1];
#pragma unroll
    for (int hh = 0; hh < 2; ++hh) {
      s16x8 af[2], bfr[4];
#pragma unroll
      for (int mi = 0; mi < 2; ++mi) {
        int row = wr * 32 + mi * 16 + llo;
        af[mi] = *(const s16x8*)&Alc[row * 64 + ((((hh << 2) | lhi) ^ (row & 7)) * 8)];
      }
#pragma unroll
      for (int ni = 0; ni < 4; ++ni) {
        int n = wc * 64 + ni * 16 + llo;
        bfr[ni] = *(const s16x8*)&Blc[n * 64 + ((((hh << 2) | lhi) ^ (n & 7)) * 8)];
      }
#pragma unroll
      for (int mi = 0; mi < 2; ++mi)
#pragma unroll
        for (int ni = 0; ni < 4; ++ni)
          acc[mi][ni] = __builtin_amdgcn_mfma_f32_16x16x32_bf16(
              af[mi], bfr[ni], acc[mi][ni], 0, 0, 0);
    }
  }

  const int b0_ = bt0 >> 4, t0_ = bt0 & 15;
  const int bt1 = bt0 + 1;
  const int b1_ = bt1 >> 4, t1_ = bt1 & 15;
  const size_t rowbase0 = (size_t)(b0_ * 576 + s0) * 16 + t0_;
  const size_t rowbase1 = (size_t)(b1_ * 576 + s0) * 16 + t1_;

  float bia[4];
#pragma unroll
  for (int ni = 0; ni < 4; ++ni)
    bia[ni] = bias[col0 + wc * 64 + ni * 16 + llo];

  if (dopv) {
    float w2[4];
#pragma unroll
    for (int ni = 0; ni < 4; ++ni) w2[ni] = Wp2[wc * 64 + ni * 16 + llo];
    float part[8];
#pragma unroll
    for (int mi = 0; mi < 2; ++mi)
#pragma unroll
      for (int i = 0; i < 4; ++i) {
        float sum = 0.f;
#pragma unroll
        for (int ni = 0; ni < 4; ++ni) {
          float x = acc[mi][ni][i] + bia[ni];
          float gg = 0.5f * x * (1.f + erff(x * 0.70710678f));
          sum += gg * w2[ni];
        }
        part[mi * 4 + i] = sum;
      }
#pragma unroll
    for (int d = 1; d < 16; d <<= 1)
#pragma unroll
      for (int idx = 0; idx < 8; ++idx)
        part[idx] += __shfl_xor(part[idx], d, 64);
    if (llo == 0) {
#pragma unroll
      for (int mi = 0; mi < 2; ++mi)
#pragma unroll
        for (int i = 0; i < 4; ++i)
          Pv[wc][wr * 32 + mi * 16 + lhi * 4 + i] = part[mi * 4 + i];
    }
    __syncthreads();
    if (tid < 128) {
      float sum = Pv[0][tid] + Pv[1][tid] + bp2[0];
      size_t rb = (tid < 64) ? (rowbase0 + (size_t)tid * 16)
                             : (rowbase1 + (size_t)(tid - 64) * 16);
      pviol[rb] = 1.f / (1.f + expf(-sum));
    }
  } else {
#pragma unroll
    for (int mi = 0; mi < 2; ++mi) {
#pragma unroll
      for (int i = 0; i < 4; ++i) {
        const int rloc = wr * 32 + mi * 16 + lhi * 4 + i;
        const size_t crow = (rloc < 64 ? rowbase0 + (size_t)rloc * 16
                                       : rowbase1 + (size_t)(rloc - 64) * 16);
        u16* cp = C + crow * NC + col0 + wc * 64 + llo;
#pragma unroll
        for (int ni = 0; ni < 4; ++ni)
          cp[ni * 16] = f2bf(acc[mi][ni][i] + bia[ni]);
      }
    }
  }
}

// ---------------------------------------------------------------------------
// Attention, MFMA version (verified R8). One wave per (n, head); no barriers.
// ---------------------------------------------------------------------------
__global__ __launch_bounds__(256) void attn_kernel(
    const u16* Q, const u16* __restrict__ KVP,
    const float* __restrict__ pviol, u16* att)
{
  __shared__ __align__(16) u16 Vl[4][16 * 72];
  __shared__ __align__(16) u16 Ol[4][16 * 72];
  const int tid = threadIdx.x;
  const int w = tid >> 6, lane = tid & 63;
  const int logical = xcd_swz(blockIdx.x, gridDim.x);
  const int wid = logical * 4 + w;
  const int n = wid >> 3, hh = wid & 7;
  const int g = lane >> 4, llo = lane & 15;

  const int r = lane >> 3, co = (lane & 7) * 8;
  {
    const u16* Vb = KVP + (size_t)n * (16 * 1152) + 512 + hh * 64;
#pragma unroll
    for (int rr = 0; rr < 2; ++rr) {
      int row = r + rr * 8;
      *(u16x8*)&Vl[w][row * 72 + co] =
          *(const u16x8*)(Vb + (size_t)row * 1152 + co);
    }
  }

  const u16* Qr = Q + ((size_t)n * 16 + llo) * 512 + hh * 64;
  const u16* Kr = KVP + ((size_t)n * 16 + llo) * 1152 + hh * 64;
  s16x8 qa0 = *(const s16x8*)(Qr + g * 8);
  s16x8 qa1 = *(const s16x8*)(Qr + 32 + g * 8);
  s16x8 ka0 = *(const s16x8*)(Kr + g * 8);
  s16x8 ka1 = *(const s16x8*)(Kr + 32 + g * 8);

  f32x4 sacc = {0.f, 0.f, 0.f, 0.f};
  sacc = __builtin_amdgcn_mfma_f32_16x16x32_bf16(ka0, qa0, sacc, 0, 0, 0);
  sacc = __builtin_amdgcn_mfma_f32_16x16x32_bf16(ka1, qa1, sacc, 0, 0, 0);
  // lane(g,llo) holds S[llo][g*4+i]

  const float* pv = pviol + n * 16;
  float s[4];
#pragma unroll
  for (int i = 0; i < 4; ++i) s[i] = sacc[i] * 0.125f - GAMMA * pv[g * 4 + i];

  float mx = fmaxf(fmaxf(s[0], s[1]), fmaxf(s[2], s[3]));
  mx = fmaxf(mx, __shfl_xor(mx, 16, 64));
  mx = fmaxf(mx, __shfl_xor(mx, 32, 64));
  float e[4], sum = 0.f;
#pragma unroll
  for (int i = 0; i < 4; ++i) { e[i] = expf(s[i] - mx); sum += e[i]; }
  sum += __shfl_xor(sum, 16, 64);
  sum += __shfl_xor(sum, 32, 64);
  float inv = 1.f / sum;

  unsigned p01 = pk_bf16(e[0] * inv, e[1] * inv);
  unsigned p23 = pk_bf16(e[2] * inv, e[3] * inv);

  const int sa = ((2 * g) & 3) * 16 + llo;
  const int sb = ((2 * g + 1) & 3) * 16 + llo;
  unsigned a0 = (unsigned)__shfl((int)p01, sa, 64);
  unsigned a1 = (unsigned)__shfl((int)p23, sa, 64);
  unsigned b0 = (unsigned)__shfl((int)p01, sb, 64);
  unsigned b1 = (unsigned)__shfl((int)p23, sb, 64);
  ui32x4 afu = {0u, 0u, 0u, 0u};
  if (g < 2) { afu[0] = a0; afu[1] = a1; afu[2] = b0; afu[3] = b1; }
  s16x8 pfrag;
  __builtin_memcpy(&pfrag, &afu, 16);

  f32x4 oacc[4];
#pragma unroll
  for (int c = 0; c < 4; ++c) {
    u16 vb[8];
#pragma unroll
    for (int j = 0; j < 8; ++j)
      vb[j] = (g < 2) ? Vl[w][(g * 8 + j) * 72 + c * 16 + llo] : (u16)0;
    s16x8 vfrag;
    __builtin_memcpy(&vfrag, vb, 16);
    f32x4 z = {0.f, 0.f, 0.f, 0.f};
    oacc[c] = __builtin_amdgcn_mfma_f32_16x16x32_bf16(pfrag, vfrag, z, 0, 0, 0);
  }

#pragma unroll
  for (int c = 0; c < 4; ++c)
#pragma unroll
    for (int i = 0; i < 4; ++i)
      Ol[w][(g * 4 + i) * 72 + c * 16 + llo] = f2bf(oacc[c][i]);

  {
    u16* ob = att + ((size_t)n * 16) * 512 + hh * 64;
#pragma unroll
    for (int rr = 0; rr < 2; ++rr) {
      int row = r + rr * 8;
      *(u16x8*)(ob + (size_t)row * 512 + co) = *(const u16x8*)&Ol[w][row * 72 + co];
    }
  }
}

// ---------------------------------------------------------------------------
// Output projection: bf16 A (row-major, stride 16*512) x WoT.
// Verified double-buffered form (R3/R4/R5): ONE __syncthreads per K-step.
// ---------------------------------------------------------------------------
__global__ __launch_bounds__(256) void gemm_out(
    const u16* __restrict__ A, const u16* __restrict__ WT,
    const float* __restrict__ bias, float* __restrict__ out)
{
  __shared__ __align__(16) char smem[49152];       // Al(16K)+Bl(32K); Cl aliases
  u16* Al0 = (u16*)smem;                           // [2][64*64]
  u16* Bl0 = (u16*)(smem + 16384);                 // [2][128*64]
  const int tid = threadIdx.x;
  const int w = tid >> 6, lane = tid & 63;
  const int lhi = lane >> 4, llo = lane & 15;

  const int nwg = gridDim.x * gridDim.y;
  const int phys = blockIdx.y * gridDim.x + blockIdx.x;
  const int logical = xcd_swz(phys, nwg);
  const int bx = logical % gridDim.x;
  const int y = logical / gridDim.x;

  const int bt = y / 9, stile = y - bt * 9;
  const int s0 = stile * 64;
  const int col0 = bx * 128;
  const int b_ = bt >> 4, t_ = bt & 15;

  const u16* Ab = A + ((size_t)(b_ * 576 + s0) * 16 + t_) * 512;
  const u16* Bb = WT + (size_t)col0 * 512;

  const int brow = lane >> 3;
  const int bko = ((lane & 7) ^ brow) * 8;

  f32x4 acc[4][2];
#pragma unroll
  for (int mi = 0; mi < 4; ++mi)
#pragma unroll
    for (int ni = 0; ni < 2; ++ni)
#pragma unroll
      for (int e = 0; e < 4; ++e) acc[mi][ni][e] = 0.f;

  // prologue: stage tiles(0)
#pragma unroll
  for (int i = 0; i < 2; ++i) {
    int q = w * 2 + i;
    gl2lds16(Ab + (size_t)(q * 8 + brow) * (16 * 512) + bko, &Al0[q * 512]);
  }
#pragma unroll
  for (int i = 0; i < 4; ++i) {
    int q = w * 4 + i;
    gl2lds16(Bb + (size_t)(q * 8 + brow) * 512 + bko, &Bl0[q * 512]);
  }

  for (int kt = 0; kt < 8; ++kt) {
    __syncthreads();  // tiles(kt) resident; prev compute reads done
    if (kt < 7) {
      const int ktn = kt + 1;
      u16* Ala = Al0 + (ktn & 1) * (64 * 64);
      u16* Bla = Bl0 + (ktn & 1) * (128 * 64);
#pragma unroll
      for (int i = 0; i < 2; ++i) {
        int q = w * 2 + i;
        gl2lds16(Ab + (size_t)(q * 8 + brow) * (16 * 512) + ktn * 64 + bko,
                 &Ala[q * 512]);
      }
#pragma unroll
      for (int i = 0; i < 4; ++i) {
        int q = w * 4 + i;
        gl2lds16(Bb + (size_t)(q * 8 + brow) * 512 + ktn * 64 + bko,
                 &Bla[q * 512]);
      }
    }
    const u16* Alc = Al0 + (kt & 1) * (64 * 64);
    const u16* Blc = Bl0 + (kt & 1) * (128 * 64);
#pragma unroll
    for (int hh = 0; hh < 2; ++hh) {
      s16x8 af[4], bfr[2];
#pragma unroll
      for (int mi = 0; mi < 4; ++mi) {
        int row = mi * 16 + llo;
        af[mi] = *(const s16x8*)&Alc[row * 64 + ((((hh << 2) | lhi) ^ (row & 7)) * 8)];
      }
#pragma unroll
      for (int ni = 0; ni < 2; ++ni) {
        int n = w * 32 + ni * 16 + llo;
        bfr[ni] = *(const s16x8*)&Blc[n * 64 + ((((hh << 2) | lhi) ^ (n & 7)) * 8)];
      }
#pragma unroll
      for (int mi = 0; mi < 4; ++mi)
#pragma unroll
        for (int ni = 0; ni < 2; ++ni)
          acc[mi][ni] = __builtin_amdgcn_mfma_f32_16x16x32_bf16(
              af[mi], bfr[ni], acc[mi][ni], 0, 0, 0);
    }
  }

  __syncthreads();
  float* Cl = (float*)smem;  // 128 (n) x 72 (m, padded) fp32
  float bia0 = bias[col0 + w * 32 + llo];
  float bia1 = bias[col0 + w * 32 + 16 + llo];
#pragma unroll
  for (int mi = 0; mi < 4; ++mi)
#pragma unroll
    for (int i = 0; i < 4; ++i) {
      int m = mi * 16 + lhi * 4 + i;
      Cl[(w * 32 + llo) * 72 + m]      = acc[mi][0][i] + bia0;
      Cl[(w * 32 + 16 + llo) * 72 + m] = acc[mi][1][i] + bia1;
    }
  __syncthreads();
  const int nn = tid >> 1;
  const int mh = (tid & 1) * 32;
  const float* sp = Cl + nn * 72 + mh;
  float* dp = out + ((size_t)bt * 512 + col0 + nn) * 576 + s0 + mh;
#pragma unroll
  for (int j = 0; j < 8; ++j)
    *(float4*)(dp + j * 4) = *(const float4*)(sp + j * 4);
}

extern "C" void kernel_launch(void* const* d_in, const int* in_sizes, int n_in,
                              void* d_out, int out_size, void* d_ws, size_t ws_size,
                              hipStream_t stream)
{
  const float* h_opt = (const float*)d_in[0];
  const float* h_sar = (const float*)d_in[1];
  const float* Wq  = (const float*)d_in[2];
  const float* bq  = (const float*)d_in[3];
  const float* Wk  = (const float*)d_in[4];
  const float* bk  = (const float*)d_in[5];
  const float* Wv  = (const float*)d_in[6];
  const float* bv  = (const float*)d_in[7];
  const float* Wo  = (const float*)d_in[8];
  const float* bo  = (const float*)d_in[9];
  const float* Wp1 = (const float*)d_in[10];
  const float* bp1 = (const float*)d_in[11];
  const float* Wp2 = (const float*)d_in[12];
  const float* bp2 = (const float*)d_in[13];
  float* out = (float*)d_out;

  char* ws = (char*)d_ws;
  u16*   WqT     = (u16*)(ws + 0);          // 512x512 bf16   (524288 B)
  u16*   KVPW    = (u16*)(ws + 524288);     // 1152x512 bf16  (1179648 B)
  u16*   WoT     = (u16*)(ws + 1703936);    // 512x512 bf16   (524288 B)
  float* biasQ   = (float*)(ws + 2228224);  // 512 f32
  float* biasKVP = (float*)(ws + 2230272);  // 1152 f32
  float* biasO   = (float*)(ws + 2234880);  // 512 f32
  float* pviol   = (float*)(ws + 2236928);  // 36864 f32
  u16*   Qbuf    = (u16*)(ws + 2384384);    // 36864x512 bf16  — also att
  u16*   KVPbuf  = (u16*)(ws + 40133120);   // 36864x1152 bf16 (84934656 B)
  u16*   hTopt   = (u16*)(ws + 125067776);  // 64x576x512 bf16 (37748736 B)
  u16*   hTsar   = (u16*)(ws + 162816512);  // 64x576x512 bf16 (37748736 B)

  prep_all<<<PREP_NB, 256, 0, stream>>>(
      h_opt, h_sar, hTopt, hTsar, Wq, Wk, Wv, Wp1, Wo,
      bq, bk, bv, bp1, bo, WqT, KVPW, WoT, biasQ, biasKVP, biasO);

  gemm_proj_all<<<dim3(13, 288), 512, 0, stream>>>(
      hTopt, hTsar, WqT, KVPW, biasQ, biasKVP, Wp2, bp2,
      Qbuf, KVPbuf, pviol);

  attn_kernel<<<4608, 256, 0, stream>>>(Qbuf, KVPbuf, pviol, Qbuf);
  gemm_out<<<dim3(4, 576), 256, 0, stream>>>(Qbuf, WoT, biasO, out);
}